// Round 3
// 422.891 us; speedup vs baseline: 1.0116x; 1.0116x over previous
//
#include <hip/hip_runtime.h>

// fp8 blockwise-quantized GEMM for MI355X (gfx950) — round 6
//   y = (fp8(x/sx)*sx) @ (fp8(w)*sw)^T
// Rounds 4/5 (counted-vmcnt double-buffer) died at container level twice.
// Audit found no certain hang, but three novel-vs-round-3 constructs are
// de-risked this round while keeping the pipeline thesis:
//  a) scale-row DMA no longer replicated by all 8 waves to one LDS address
//     (untested arbitration): wave 0 stages it alone; per-wave counted waits
//     vmcnt(9) for wave 0, vmcnt(8) for waves 1-7 (vmcnt is per-wave).
//  b) raw s_barrier is now followed by a memory-clobber fence +
//     sched_barrier(0): LLVM's s_barrier is not a memory fence, so LDS reads
//     that depend on OTHER waves' DMAs could have been hoisted above it.
//  c) bottom sync is plain __syncthreads() (proven) instead of manual
//     lgkmcnt(0)+s_barrier. Drain at the bottom is tail-only: the batch was
//     issued BEFORE the compute phase, so overlap is preserved.

typedef int   v4i __attribute__((ext_vector_type(4)));
typedef int   v8i __attribute__((ext_vector_type(8)));
typedef float v4f __attribute__((ext_vector_type(4)));

constexpr int M  = 8192;
constexpr int K  = 4096;
constexpr int N  = 4096;
constexpr int KB = K / 128;  // 32
constexpr int NB = N / 128;  // 32

constexpr int XBLOCKS = (M * KB * 8) / 256;                    // 8192
constexpr int WBLOCKS = (int)(((long long)N * K / 16) / 256);  // 4096

#define GLOBAL_AS __attribute__((address_space(1)))
#define LDS_AS    __attribute__((address_space(3)))

__device__ __forceinline__ void async16(const void* g, void* l) {
  // 16B/lane global->LDS DMA; LDS dest = wave-uniform base (+ lane*16 by HW)
  __builtin_amdgcn_global_load_lds((const GLOBAL_AS void*)g, (LDS_AS void*)l, 16, 0, 0);
}

// Fragment-order layout for quantized Q[R][K]:
//   group (rf = r>>4, kb = k>>7) at base (rf*KB + kb)*2048
//   lane l = (k-quad)*16 + (r&15); lo16 @ base + l*16, hi16 @ base + 1024 + l*16
// matches the 16x16x128 f8f6f4 A/B operand layout (HW-validated rounds 1-3).

// ---------------- fused activation + weight quant ------------------------
__global__ __launch_bounds__(256) void quant_fused_kernel(
    const float* __restrict__ x, const float* __restrict__ w,
    unsigned char* __restrict__ xq, unsigned char* __restrict__ wq,
    float* __restrict__ xs_t /* [KB][M] */) {
  const int tid = threadIdx.x;
  if (blockIdx.x < XBLOCKS) {
    // ---- activation blockwise quant (fragment-order output) ----
    const long long blk = ((long long)blockIdx.x * 256 + tid) >> 3;  // over M*KB
    const int s = tid & 7;
    const int m  = (int)(blk >> 5);        // KB = 32
    const int kb = (int)(blk & (KB - 1));

    const float4* px = (const float4*)(x + blk * 128 + s * 16);
    float4 v0 = px[0], v1 = px[1], v2 = px[2], v3 = px[3];

    float ax = 0.f;
#define AMAX4(v) ax = fmaxf(ax, fmaxf(fmaxf(fabsf(v.x), fabsf(v.y)), fmaxf(fabsf(v.z), fabsf(v.w))))
    AMAX4(v0); AMAX4(v1); AMAX4(v2); AMAX4(v3);
#undef AMAX4
#pragma unroll
    for (int d = 4; d >= 1; d >>= 1) ax = fmaxf(ax, __shfl_xor(ax, d, 8));
    const float scale = fmaxf(ax, 1e-12f) / 448.0f;  // matches reference RNE path

    int p0 = 0, p1 = 0, p2 = 0, p3 = 0;
    p0 = __builtin_amdgcn_cvt_pk_fp8_f32(v0.x / scale, v0.y / scale, p0, false);
    p0 = __builtin_amdgcn_cvt_pk_fp8_f32(v0.z / scale, v0.w / scale, p0, true);
    p1 = __builtin_amdgcn_cvt_pk_fp8_f32(v1.x / scale, v1.y / scale, p1, false);
    p1 = __builtin_amdgcn_cvt_pk_fp8_f32(v1.z / scale, v1.w / scale, p1, true);
    p2 = __builtin_amdgcn_cvt_pk_fp8_f32(v2.x / scale, v2.y / scale, p2, false);
    p2 = __builtin_amdgcn_cvt_pk_fp8_f32(v2.z / scale, v2.w / scale, p2, true);
    p3 = __builtin_amdgcn_cvt_pk_fp8_f32(v3.x / scale, v3.y / scale, p3, false);
    p3 = __builtin_amdgcn_cvt_pk_fp8_f32(v3.z / scale, v3.w / scale, p3, true);

    const int q = s >> 1, j = s & 1, rr = m & 15;
    const long long base = ((long long)(m >> 4) * KB + kb) * 2048;
    *(v4i*)(xq + base + j * 1024 + (q * 16 + rr) * 16) = (v4i){p0, p1, p2, p3};

    if (s == 0) xs_t[(long long)kb * M + m] = scale;
  } else {
    // ---- weight fp8 cast (fragment-order output) ----
    const long long t = (long long)(blockIdx.x - XBLOCKS) * 256 + tid;  // N*K/16
    const int grp = (int)(t >> 7);
    const int idx = (int)(t & 127);
    const int l = idx >> 1, j = idx & 1;
    const int nf = grp >> 5, kb = grp & (KB - 1);
    const int n = nf * 16 + (l & 15);
    const int k = kb * 128 + (l >> 4) * 32 + j * 16;

    const float4* pw = (const float4*)(w + (long long)n * K + k);
    float4 v0 = pw[0], v1 = pw[1], v2 = pw[2], v3 = pw[3];
    int p0 = 0, p1 = 0, p2 = 0, p3 = 0;
    p0 = __builtin_amdgcn_cvt_pk_fp8_f32(v0.x, v0.y, p0, false);
    p0 = __builtin_amdgcn_cvt_pk_fp8_f32(v0.z, v0.w, p0, true);
    p1 = __builtin_amdgcn_cvt_pk_fp8_f32(v1.x, v1.y, p1, false);
    p1 = __builtin_amdgcn_cvt_pk_fp8_f32(v1.z, v1.w, p1, true);
    p2 = __builtin_amdgcn_cvt_pk_fp8_f32(v2.x, v2.y, p2, false);
    p2 = __builtin_amdgcn_cvt_pk_fp8_f32(v2.z, v2.w, p2, true);
    p3 = __builtin_amdgcn_cvt_pk_fp8_f32(v3.x, v3.y, p3, false);
    p3 = __builtin_amdgcn_cvt_pk_fp8_f32(v3.z, v3.w, p3, true);
    *(v4i*)(wq + (long long)grp * 2048 + j * 1024 + l * 16) = (v4i){p0, p1, p2, p3};
  }
}

// ---------------- double-buffered fp8 GEMM, 256x256 block tile ----------
// grid (N/256, M/256), 512 threads = 8 waves (wm 0..1 x wn 0..3); wave tile
// 128x64 = Fa8 x Fb4 fragments. Per kb-step each wave stages 8 x 1KB tile
// DMAs (wave 0: +1 scale-row DMA) into the *next* buffer, waits a COUNTED
// vmcnt for its own previous batch, raw-barriers, computes; bottom sync is
// __syncthreads() (tail-only drain: the batch was issued before compute).
__global__ __launch_bounds__(512, 2) void gemm_fp8_kernel(
    const unsigned char* __restrict__ xq, const unsigned char* __restrict__ wq,
    const float* __restrict__ xs_t /*[KB][M]*/,
    const float* __restrict__ wscale /*[NB][KB]*/,
    float* __restrict__ out) {
  __shared__ unsigned char Asm[2][16 * 2048];  // 64 KB: 16 A frag-groups x2
  __shared__ unsigned char Bsm[2][16 * 2048];  // 64 KB: 16 B frag-groups x2
  __shared__ float Ssm[2][256];                // 2 KB: x-scale row x2

  const int tid   = threadIdx.x;
  const int ntile = blockIdx.x;  // 0..15 (256-col tiles)
  const int mtile = blockIdx.y;  // 0..31 (256-row tiles)
  const int wave  = tid >> 6;    // 0..7
  const int lane  = tid & 63;
  const int wm = wave >> 2, wn = wave & 3;
  const int l15 = lane & 15, quad = lane >> 4;

  // per-wave w-scale: lane k (k<32) holds wscale[nblock(wave)][k]; the wave's
  // 64 columns sit inside ONE 128-col scale block, so ws is wave-uniform and
  // readlane(wsv, kb) broadcasts it each iteration.
  const float wsv = wscale[(ntile * 2 + (wn >> 1)) * KB + (lane & 31)];

  // staging base pointers (per-lane global addresses; LDS dests wave-uniform)
  const unsigned char* pa0 =
      xq + ((long long)(mtile * 16 + wave * 2) * KB) * 2048 + lane * 16;
  const unsigned char* pb0 =
      wq + ((long long)(ntile * 16 + wave * 2) * KB) * 2048 + lane * 16;
  const char* ps0 = (const char*)(xs_t + (long long)mtile * 256) + lane * 16;

  auto STAGE = [&](int nbuf, int kbi) {
    const long long koff = (long long)kbi * 2048;
#pragma unroll
    for (int t = 0; t < 4; ++t)  // A: group wave*2 + (t>>1), half t&1
      async16(pa0 + koff + (long long)(t >> 1) * (KB * 2048) + (t & 1) * 1024,
              &Asm[nbuf][(wave * 2 + (t >> 1)) * 2048 + (t & 1) * 1024]);
#pragma unroll
    for (int t = 0; t < 4; ++t)  // B: group wave*2 + (t>>1), half t&1
      async16(pb0 + koff + (long long)(t >> 1) * (KB * 2048) + (t & 1) * 1024,
              &Bsm[nbuf][(wave * 2 + (t >> 1)) * 2048 + (t & 1) * 1024]);
    // x-scale row (1KB): staged by wave 0 only. vmcnt is per-wave, so wave 0
    // simply counts one more outstanding DMA than waves 1-7.
    if (wave == 0) async16(ps0 + (long long)kbi * (M * 4), &Ssm[nbuf][0]);
  };

  v4f acc[8][4];
#pragma unroll
  for (int f = 0; f < 8; ++f)
#pragma unroll
    for (int g = 0; g < 4; ++g) acc[f][g] = (v4f){0.f, 0.f, 0.f, 0.f};

  const v4f z = (v4f){0.f, 0.f, 0.f, 0.f};

  STAGE(0, 0);  // prologue prefetch

#pragma unroll 1
  for (int kb = 0; kb < KB; ++kb) {
    const int cur = kb & 1;
    if (kb < KB - 1) {
      STAGE(cur ^ 1, kb + 1);  // next-buffer batch; stays in flight over compute
      // wait only for THIS WAVE's previous batch (FIFO-oldest):
      if (wave == 0) asm volatile("s_waitcnt vmcnt(9)" ::: "memory");
      else           asm volatile("s_waitcnt vmcnt(8)" ::: "memory");
    } else {
      asm volatile("s_waitcnt vmcnt(0)" ::: "memory");
    }
    __builtin_amdgcn_s_barrier();  // everyone's cur-buffer DMAs retired
    // s_barrier is not an IR memory fence: pin cross-wave-dependent LDS reads
    // below it (compiler fence + scheduler fence).
    asm volatile("" ::: "memory");
    __builtin_amdgcn_sched_barrier(0);

    const float ws =
        __uint_as_float(__builtin_amdgcn_readlane(__float_as_uint(wsv), kb));

    // ---- B fragments (shared across all f) ----
    v8i b[4];
#pragma unroll
    for (int g = 0; g < 4; ++g) {
      const unsigned char* pb = Bsm[cur] + (wn * 4 + g) * 2048 + lane * 16;
      v4i lo = *(const v4i*)pb;
      v4i hi = *(const v4i*)(pb + 1024);
      b[g][0] = lo[0]; b[g][1] = lo[1]; b[g][2] = lo[2]; b[g][3] = lo[3];
      b[g][4] = hi[0]; b[g][5] = hi[1]; b[g][6] = hi[2]; b[g][7] = hi[3];
    }

    // ---- per A-fragment: load, 4 MFMA, exact f32 rescale ----
#pragma unroll
    for (int f = 0; f < 8; ++f) {
      const unsigned char* pa = Asm[cur] + (wm * 8 + f) * 2048 + lane * 16;
      v4i lo = *(const v4i*)pa;
      v4i hi = *(const v4i*)(pa + 1024);
      v8i a;
      a[0] = lo[0]; a[1] = lo[1]; a[2] = lo[2]; a[3] = lo[3];
      a[4] = hi[0]; a[5] = hi[1]; a[6] = hi[2]; a[7] = hi[3];
      const v4f sxr = *(const v4f*)&Ssm[cur][wm * 128 + f * 16 + quad * 4];
      const v4f s = sxr * ws;
      v4f p[4];
      __builtin_amdgcn_s_setprio(1);
#pragma unroll
      for (int g = 0; g < 4; ++g) {
        // unit e8m0 scales (0x7F = 2^0): plain fp8 K=128 dot at MX rate
        p[g] = __builtin_amdgcn_mfma_scale_f32_16x16x128_f8f6f4(
            a, b[g], z, 0, 0, 0, 0x7f7f7f7f, 0, 0x7f7f7f7f);
      }
      __builtin_amdgcn_s_setprio(0);
#pragma unroll
      for (int g = 0; g < 4; ++g) acc[f][g] += s * p[g];
    }
    // bottom sync: proven construct. Drains this iteration's prefetch batch,
    // but that batch has had the whole compute phase to land (tail-only cost),
    // and guarantees cur's LDS reads are done before next-iter overwrite.
    __syncthreads();
  }

  // ---- epilogue: C/D layout col = lane&15, row = quad*4 + reg ----
#pragma unroll
  for (int f = 0; f < 8; ++f) {
#pragma unroll
    for (int r = 0; r < 4; ++r) {
      const long long row = mtile * 256 + wm * 128 + f * 16 + quad * 4 + r;
      float* po = out + row * N + ntile * 256 + wn * 64 + l15;
#pragma unroll
      for (int g = 0; g < 4; ++g) po[g * 16] = acc[f][g][r];
    }
  }
}

extern "C" void kernel_launch(void* const* d_in, const int* in_sizes, int n_in,
                              void* d_out, int out_size, void* d_ws, size_t ws_size,
                              hipStream_t stream) {
  const float* x   = (const float*)d_in[0];  // [M,K]
  const float* w   = (const float*)d_in[1];  // [N,K]
  const float* wsc = (const float*)d_in[2];  // [NB,KB]
  float* out = (float*)d_out;                // [M,N] f32

  unsigned char* ws = (unsigned char*)d_ws;
  unsigned char* xq = ws;                                      // 32 MB frag-order
  unsigned char* wq = ws + (size_t)M * K;                      // 16 MB frag-order
  float* xs_t = (float*)(ws + (size_t)M * K + (size_t)N * K);  // 1 MB [KB][M]

  quant_fused_kernel<<<XBLOCKS + WBLOCKS, 256, 0, stream>>>(x, w, xq, wq, xs_t);
  gemm_fp8_kernel<<<dim3(N / 256, M / 256), 512, 0, stream>>>(xq, wq, xs_t, wsc, out);
}